// Round 6
// baseline (3740.052 us; speedup 1.0000x reference)
//
#include <hip/hip_runtime.h>
#include <hip/hip_bf16.h>
#include <stdint.h>

typedef unsigned short u16;

#define T_TOK 8192
#define DIM 2048
#define INTER 1408
#define NEXP 32
#define TOPK 6
#define SHINTER 2816
#define SLOTS (T_TOK * TOPK)   // 49152

typedef __attribute__((ext_vector_type(8))) short bf16x8;
typedef __attribute__((ext_vector_type(4))) float f32x4;

__device__ inline u16 f2bf(float f) {
  union { float f; unsigned u; } c; c.f = f;
  unsigned r = (c.u + 0x7FFFu + ((c.u >> 16) & 1u)) >> 16;
  return (u16)r;
}
__device__ inline float bf2f(u16 h) {
  union { unsigned u; float f; } c; c.u = ((unsigned)h) << 16;
  return c.f;
}

__device__ __forceinline__ void gl16(const void* g, void* l) {
  __builtin_amdgcn_global_load_lds(
      (const __attribute__((address_space(1))) void*)g,
      (__attribute__((address_space(3))) void*)l, 16, 0, 0);
}

// ---------------- gate + routing ----------------
__global__ __launch_bounds__(256)
void gate_route_k(const float* __restrict__ x, const float* __restrict__ gw,
                  int* __restrict__ tidx, float* __restrict__ tw, int* __restrict__ counts)
{
  int lane = threadIdx.x & 63, w = threadIdx.x >> 6;
  int t = blockIdx.x * 4 + w;
  __shared__ float sc[4][32];
  __shared__ float gm[4][8];
  const float* xr = x + (size_t)t * DIM + lane * 4;
  float4 xv[8];
#pragma unroll
  for (int i = 0; i < 8; i++) xv[i] = *(const float4*)(xr + i * 256);
  for (int e = 0; e < NEXP; e++) {
    const float* g = gw + (size_t)e * DIM + lane * 4;
    float acc = 0.f;
#pragma unroll
    for (int i = 0; i < 8; i++) {
      float4 gv = *(const float4*)(g + i * 256);
      acc += xv[i].x * gv.x + xv[i].y * gv.y + xv[i].z * gv.z + xv[i].w * gv.w;
    }
#pragma unroll
    for (int off = 32; off > 0; off >>= 1) acc += __shfl_down(acc, off);
    if (lane == 0) sc[w][e] = 1.f / (1.f + __expf(-acc));
  }
  if (lane == 0) {
#pragma unroll
    for (int g = 0; g < 8; g++)
      gm[w][g] = fmaxf(fmaxf(sc[w][g*4+0], sc[w][g*4+1]), fmaxf(sc[w][g*4+2], sc[w][g*4+3]));
    unsigned gsel = 0u;
    for (int it = 0; it < 4; it++) {
      float best = -1.f; int bi = 0;
      for (int g = 0; g < 8; g++)
        if (!((gsel >> g) & 1u) && gm[w][g] > best) { best = gm[w][g]; bi = g; }
      gsel |= 1u << bi;
    }
    unsigned chosen = 0u; float wsum = 0.f;
    int ids[TOPK]; float wv[TOPK];
#pragma unroll
    for (int it = 0; it < TOPK; it++) {
      float best = -1.f; int bi = 0;
      for (int e = 0; e < NEXP; e++)
        if (((gsel >> (e >> 2)) & 1u) && !((chosen >> e) & 1u) && sc[w][e] > best) { best = sc[w][e]; bi = e; }
      chosen |= 1u << bi; ids[it] = bi; wv[it] = best; wsum += best;
    }
    float s = 2.5f / wsum;
#pragma unroll
    for (int k = 0; k < TOPK; k++) {
      tidx[t * TOPK + k] = ids[k];
      tw[t * TOPK + k] = wv[k] * s;
      atomicAdd(&counts[ids[k]], 1);
    }
  }
}

__global__ void zero32(int* p) { if (threadIdx.x < NEXP) p[threadIdx.x] = 0; }

// ---------------- scan + tile descriptors (single wave, shfl prefix) --------
__global__ void scan_desc_k(const int* __restrict__ counts, int* __restrict__ offs,
                            int4* __restrict__ desc128, int* __restrict__ ntiles)
{
  int lane = threadIdx.x;                      // 64 threads, one wave
  int c = (lane < NEXP) ? counts[lane] : 0;
  // inclusive prefix of counts
  int inc = c;
#pragma unroll
  for (int d = 1; d < 64; d <<= 1) {
    int v = __shfl_up(inc, d);
    if (lane >= d) inc += v;
  }
  int off_e = inc - c;                          // exclusive
  int nt = (c + 127) >> 7;
  int tinc = nt;
#pragma unroll
  for (int d = 1; d < 64; d <<= 1) {
    int v = __shfl_up(tinc, d);
    if (lane >= d) tinc += v;
  }
  int tex = tinc - nt;
  if (lane < NEXP) {
    offs[lane] = off_e;
    for (int i = 0; i < nt; i++) {
      int rem = c - i * 128;
      desc128[tex + i] = make_int4(lane, off_e + i * 128, rem < 128 ? rem : 128, 0);
    }
  }
  if (lane == NEXP - 1) {
    offs[NEXP] = inc;
    ntiles[0] = tinc;
  }
}

// ---------------- deterministic permutation build ----------------
__global__ __launch_bounds__(1024)
void perm_build_k(const int* __restrict__ tidx, const float* __restrict__ tw,
                  const int* __restrict__ offs, int* __restrict__ ptok,
                  float* __restrict__ pw, int* __restrict__ slotof)
{
  int e = blockIdx.x;
  int tid = threadIdx.x, lane = tid & 63, w = tid >> 6;   // 16 waves
  __shared__ int wsum[16];
  __shared__ int cursor;
  if (tid == 0) cursor = offs[e];
  __syncthreads();
  for (int start = 0; start < SLOTS; start += 1024) {
    int i = start + tid;
    int match = (tidx[i] == e) ? 1 : 0;
    unsigned long long b = __ballot(match);
    if (lane == 0) wsum[w] = __popcll(b);
    __syncthreads();
    int base = cursor;
    int waveoff = 0;
    for (int ww = 0; ww < w; ww++) waveoff += wsum[ww];
    int total = 0;
#pragma unroll
    for (int ww = 0; ww < 16; ww++) total += wsum[ww];
    if (match) {
      int before = __popcll(b & ((1ull << lane) - 1ull));
      int slot = base + waveoff + before;
      ptok[slot] = i / TOPK;
      pw[slot] = tw[i];
      slotof[i] = slot;
    }
    __syncthreads();
    if (tid == 0) cursor = base + total;
  }
}

// ---------------- f32 -> bf16 conversion ----------------
__global__ __launch_bounds__(256)
void cvt_w_k(const float* __restrict__ src, u16* __restrict__ dst, int n8)
{
  int stride = gridDim.x * 256;
  for (size_t i = (size_t)blockIdx.x * 256 + threadIdx.x; i < (size_t)n8; i += stride) {
    size_t j = i * 8;
    float4 a = *(const float4*)(src + j);
    float4 b = *(const float4*)(src + j + 4);
    union { u16 h[8]; uint4 u; } p;
    p.h[0] = f2bf(a.x); p.h[1] = f2bf(a.y); p.h[2] = f2bf(a.z); p.h[3] = f2bf(a.w);
    p.h[4] = f2bf(b.x); p.h[5] = f2bf(b.y); p.h[6] = f2bf(b.z); p.h[7] = f2bf(b.w);
    *(uint4*)(dst + j) = p.u;
  }
}

// ============================================================================
// MAIN PATH (R2-verified engine + XCD swizzle + 3 blocks/CU):
// 128^2 tile, BK=64, all-gl16 staging, XOR-swizzled linear LDS, 2 barriers/step.
// Swizzle: write src chunk (l&7)^(l>>3) at dest chunk (l&7), row l>>3 per group;
// read chunk (h*4 + (lane>>4)) ^ (lane&7). Verified r2 (absmax pass, conflicts 0).
// ============================================================================

// fused up-GEMM: H = silu(X W1^T) * (X W3^T)
template<bool SHARED>
__global__ __launch_bounds__(256, 3)
void up2_k(const u16* __restrict__ xb,
           const u16* __restrict__ B1g, const u16* __restrict__ B3g,
           const int* __restrict__ ptok,
           const int4* __restrict__ desc, const int* __restrict__ ntiles,
           u16* __restrict__ Hout)
{
  constexpr int HLD = SHARED ? SHINTER : INTER;
  int rt0 = blockIdx.x;
  int row_tile = (rt0 & 7) * (int)(gridDim.x >> 3) + (rt0 >> 3);   // XCD swizzle
  int col_tile = blockIdx.y;
  int slot_base, rows;
  const u16 *B1, *B3;
  if constexpr (SHARED) { slot_base = row_tile * 128; rows = 128; B1 = B1g; B3 = B3g; }
  else {
    if (row_tile >= ntiles[0]) return;
    int4 d = desc[row_tile];
    slot_base = d.y; rows = d.z;
    size_t off = (size_t)d.x * (size_t)INTER * DIM;
    B1 = B1g + off; B3 = B3g + off;
  }
  int n0 = col_tile * 128;
  int tid = threadIdx.x, lane = tid & 63;
  int w = tid >> 6, wr = w >> 1, wc = w & 1;

  __shared__ u16 As[128][64];
  __shared__ u16 Bs1[128][64];
  __shared__ u16 Bs3[128][64];

  int selem = (((lane & 7) ^ (lane >> 3)) * 8);
  const u16 *a_src[4], *b1_src[4], *b3_src[4];
#pragma unroll
  for (int s = 0; s < 4; s++) {
    int r = w * 32 + s * 8 + (lane >> 3);
    int tok;
    if constexpr (SHARED) tok = slot_base + r;
    else { int rr = r < rows ? r : rows - 1; tok = ptok[slot_base + rr]; }
    a_src[s]  = xb + (size_t)tok * DIM + selem;
    b1_src[s] = B1 + (size_t)(n0 + r) * DIM + selem;
    b3_src[s] = B3 + (size_t)(n0 + r) * DIM + selem;
  }

  f32x4 acc1[4][4], acc3[4][4];
#pragma unroll
  for (int m = 0; m < 4; m++)
#pragma unroll
    for (int n = 0; n < 4; n++) { acc1[m][n] = {0.f,0.f,0.f,0.f}; acc3[m][n] = {0.f,0.f,0.f,0.f}; }

  for (int kk = 0; kk < DIM / 64; kk++) {
    __syncthreads();
#pragma unroll
    for (int s = 0; s < 4; s++) {
      gl16(a_src[s]  + kk * 64, &As [w * 32 + s * 8][0]);
      gl16(b1_src[s] + kk * 64, &Bs1[w * 32 + s * 8][0]);
      gl16(b3_src[s] + kk * 64, &Bs3[w * 32 + s * 8][0]);
    }
    __syncthreads();
#pragma unroll
    for (int h = 0; h < 2; h++) {
      bf16x8 af[4], b1f[4], b3f[4];
      int chk = (h * 4 + (lane >> 4)) ^ (lane & 7);
#pragma unroll
      for (int m = 0; m < 4; m++)
        af[m] = *(const bf16x8*)&As[wr * 64 + m * 16 + (lane & 15)][chk * 8];
#pragma unroll
      for (int n = 0; n < 4; n++) {
        b1f[n] = *(const bf16x8*)&Bs1[wc * 64 + n * 16 + (lane & 15)][chk * 8];
        b3f[n] = *(const bf16x8*)&Bs3[wc * 64 + n * 16 + (lane & 15)][chk * 8];
      }
#pragma unroll
      for (int m = 0; m < 4; m++)
#pragma unroll
        for (int n = 0; n < 4; n++) {
          acc1[m][n] = __builtin_amdgcn_mfma_f32_16x16x32_bf16(af[m], b1f[n], acc1[m][n], 0, 0, 0);
          acc3[m][n] = __builtin_amdgcn_mfma_f32_16x16x32_bf16(af[m], b3f[n], acc3[m][n], 0, 0, 0);
        }
    }
  }
#pragma unroll
  for (int m = 0; m < 4; m++) {
#pragma unroll
    for (int r = 0; r < 4; r++) {
      int row_local = wr * 64 + m * 16 + (lane >> 4) * 4 + r;
      if (row_local < rows) {
        size_t rowp = (size_t)(slot_base + row_local) * HLD + n0 + wc * 64 + (lane & 15);
#pragma unroll
        for (int n = 0; n < 4; n++) {
          float c1 = acc1[m][n][r], c3 = acc3[m][n][r];
          float hval = (c1 / (1.f + __expf(-c1))) * c3;
          Hout[rowp + n * 16] = f2bf(hval);
        }
      }
    }
  }
}

// down-GEMM: O = H W2^T (+route-weight scale for routed path)
template<bool SHARED>
__global__ __launch_bounds__(256, 3)
void down2_k(const u16* __restrict__ Hin, const u16* __restrict__ Bg,
             const int4* __restrict__ desc, const int* __restrict__ ntiles,
             const float* __restrict__ pw,
             u16* __restrict__ slotout, float* __restrict__ yout)
{
  constexpr int KD = SHARED ? SHINTER : INTER;
  constexpr int KSTEPS = KD / 64;
  int rt0 = blockIdx.x;
  int row_tile = (rt0 & 7) * (int)(gridDim.x >> 3) + (rt0 >> 3);   // XCD swizzle
  int col_tile = blockIdx.y;
  int slot_base, rows; const u16* B;
  if constexpr (SHARED) { slot_base = row_tile * 128; rows = 128; B = Bg; }
  else {
    if (row_tile >= ntiles[0]) return;
    int4 d = desc[row_tile]; slot_base = d.y; rows = d.z;
    B = Bg + (size_t)d.x * DIM * INTER;
  }
  int n0 = col_tile * 128;
  int tid = threadIdx.x, lane = tid & 63;
  int w = tid >> 6, wr = w >> 1, wc = w & 1;
  __shared__ u16 As[128][64];
  __shared__ u16 Bs[128][64];

  int selem = (((lane & 7) ^ (lane >> 3)) * 8);
  const u16 *a_src[4], *b_src[4];
#pragma unroll
  for (int s = 0; s < 4; s++) {
    int r = w * 32 + s * 8 + (lane >> 3);
    a_src[s] = Hin + (size_t)(slot_base + r) * KD + selem;
    b_src[s] = B + (size_t)(n0 + r) * KD + selem;
  }

  f32x4 acc[4][4];
#pragma unroll
  for (int m = 0; m < 4; m++)
#pragma unroll
    for (int n = 0; n < 4; n++) acc[m][n] = {0.f,0.f,0.f,0.f};

  for (int kk = 0; kk < KSTEPS; kk++) {
    __syncthreads();
#pragma unroll
    for (int s = 0; s < 4; s++) {
      gl16(a_src[s] + kk * 64, &As[w * 32 + s * 8][0]);
      gl16(b_src[s] + kk * 64, &Bs[w * 32 + s * 8][0]);
    }
    __syncthreads();
#pragma unroll
    for (int h = 0; h < 2; h++) {
      bf16x8 af[4], bfv[4];
      int chk = (h * 4 + (lane >> 4)) ^ (lane & 7);
#pragma unroll
      for (int m = 0; m < 4; m++)
        af[m] = *(const bf16x8*)&As[wr * 64 + m * 16 + (lane & 15)][chk * 8];
#pragma unroll
      for (int n = 0; n < 4; n++)
        bfv[n] = *(const bf16x8*)&Bs[wc * 64 + n * 16 + (lane & 15)][chk * 8];
#pragma unroll
      for (int m = 0; m < 4; m++)
#pragma unroll
        for (int n = 0; n < 4; n++)
          acc[m][n] = __builtin_amdgcn_mfma_f32_16x16x32_bf16(af[m], bfv[n], acc[m][n], 0, 0, 0);
    }
  }
#pragma unroll
  for (int m = 0; m < 4; m++) {
#pragma unroll
    for (int r = 0; r < 4; r++) {
      int row_local = wr * 64 + m * 16 + (lane >> 4) * 4 + r;
      if (row_local < rows) {
        int slot = slot_base + row_local;
        size_t rp = (size_t)slot * DIM + n0 + wc * 64 + (lane & 15);
        if constexpr (SHARED) {
#pragma unroll
          for (int n = 0; n < 4; n++) yout[rp + n * 16] = acc[m][n][r];
        } else {
          float sw = pw[slot];
#pragma unroll
          for (int n = 0; n < 4; n++) slotout[rp + n * 16] = f2bf(acc[m][n][r] * sw);
        }
      }
    }
  }
}

// ============================================================================
// FALLBACK PATH (f32 weights, 128^2 reg-staged) — used only if ws too small
// ============================================================================
template<bool SHARED>
__global__ __launch_bounds__(256, 2)
void up_gemm_k(const u16* __restrict__ xb,
               const float* __restrict__ W1g, const float* __restrict__ W3g,
               const int* __restrict__ ptok,
               const int4* __restrict__ desc, const int* __restrict__ ntiles,
               u16* __restrict__ Hout)
{
  constexpr int HLD = SHARED ? SHINTER : INTER;
  int row_tile = blockIdx.x, col_tile = blockIdx.y;
  int slot_base, rows;
  const float *B1, *B3;
  if constexpr (SHARED) {
    slot_base = row_tile * 128; rows = 128; B1 = W1g; B3 = W3g;
  } else {
    if (row_tile >= ntiles[0]) return;
    int4 d = desc[row_tile];
    slot_base = d.y; rows = d.z;
    size_t off = (size_t)d.x * (size_t)INTER * DIM;
    B1 = W1g + off; B3 = W3g + off;
  }
  int n0 = col_tile * 128;
  int tid = threadIdx.x, lane = tid & 63;
  int wv = tid >> 6, wr = wv >> 1, wc = wv & 1;

  __shared__ u16 As[128][72];
  __shared__ u16 Bs1[128][72];
  __shared__ u16 Bs3[128][72];

  int ar = tid >> 3, ac = (tid & 7) * 8;
  const u16* asrc[4];
#pragma unroll
  for (int s = 0; s < 4; s++) {
    int r = s * 32 + ar;
    int tok;
    if constexpr (SHARED) tok = slot_base + r;
    else { int rr = r < rows ? r : rows - 1; tok = ptok[slot_base + rr]; }
    asrc[s] = xb + (size_t)tok * DIM + ac;
  }
  int br = tid >> 4, bc = (tid & 15) * 4;
  const float* b1p = B1 + (size_t)(n0 + br) * DIM + bc;
  const float* b3p = B3 + (size_t)(n0 + br) * DIM + bc;

  f32x4 acc1[4][4], acc3[4][4];
#pragma unroll
  for (int m = 0; m < 4; m++)
#pragma unroll
    for (int n = 0; n < 4; n++) { acc1[m][n] = {0.f,0.f,0.f,0.f}; acc3[m][n] = {0.f,0.f,0.f,0.f}; }

  for (int kk = 0; kk < DIM / 64; kk++) {
    __syncthreads();
#pragma unroll
    for (int s = 0; s < 4; s++) {
      uint4 v = *(const uint4*)(asrc[s] + kk * 64);
      *(uint4*)&As[s * 32 + ar][ac] = v;
    }
#pragma unroll
    for (int s = 0; s < 8; s++) {
      float4 v = *(const float4*)(b1p + (size_t)(s * 16) * DIM + kk * 64);
      union { u16 h[4]; uint2 q; } o;
      o.h[0] = f2bf(v.x); o.h[1] = f2bf(v.y); o.h[2] = f2bf(v.z); o.h[3] = f2bf(v.w);
      *(uint2*)&Bs1[s * 16 + br][bc] = o.q;
    }
#pragma unroll
    for (int s = 0; s < 8; s++) {
      float4 v = *(const float4*)(b3p + (size_t)(s * 16) * DIM + kk * 64);
      union { u16 h[4]; uint2 q; } o;
      o.h[0] = f2bf(v.x); o.h[1] = f2bf(v.y); o.h[2] = f2bf(v.z); o.h[3] = f2bf(v.w);
      *(uint2*)&Bs3[s * 16 + br][bc] = o.q;
    }
    __syncthreads();
#pragma unroll
    for (int h = 0; h < 2; h++) {
      bf16x8 af[4], b1f[4], b3f[4];
#pragma unroll
      for (int m = 0; m < 4; m++)
        af[m] = *(const bf16x8*)&As[wr * 64 + m * 16 + (lane & 15)][h * 32 + (lane >> 4) * 8];
#pragma unroll
      for (int n = 0; n < 4; n++) {
        b1f[n] = *(const bf16x8*)&Bs1[wc * 64 + n * 16 + (lane & 15)][h * 32 + (lane >> 4) * 8];
        b3f[n] = *(const bf16x8*)&Bs3[wc * 64 + n * 16 + (lane & 15)][h * 32 + (lane >> 4) * 8];
      }
#pragma unroll
      for (int m = 0; m < 4; m++)
#pragma unroll
        for (int n = 0; n < 4; n++) {
          acc1[m][n] = __builtin_amdgcn_mfma_f32_16x16x32_bf16(af[m], b1f[n], acc1[m][n], 0, 0, 0);
          acc3[m][n] = __builtin_amdgcn_mfma_f32_16x16x32_bf16(af[m], b3f[n], acc3[m][n], 0, 0, 0);
        }
    }
  }
#pragma unroll
  for (int m = 0; m < 4; m++) {
#pragma unroll
    for (int r = 0; r < 4; r++) {
      int row_local = wr * 64 + m * 16 + (lane >> 4) * 4 + r;
      if (row_local < rows) {
        size_t rowp = (size_t)(slot_base + row_local) * HLD + n0 + wc * 64 + (lane & 15);
#pragma unroll
        for (int n = 0; n < 4; n++) {
          float c1 = acc1[m][n][r], c3 = acc3[m][n][r];
          float hval = (c1 / (1.f + __expf(-c1))) * c3;
          Hout[rowp + n * 16] = f2bf(hval);
        }
      }
    }
  }
}

template<bool SHARED>
__global__ __launch_bounds__(256, 2)
void down_gemm_k(const u16* __restrict__ Hin, const float* __restrict__ Bg,
                 const int4* __restrict__ desc, const int* __restrict__ ntiles,
                 const float* __restrict__ pw,
                 u16* __restrict__ slotout, float* __restrict__ yout)
{
  constexpr int KD = SHARED ? SHINTER : INTER;
  constexpr int KSTEPS = KD / 64;
  int row_tile = blockIdx.x, col_tile = blockIdx.y;
  int slot_base, rows; const float* B;
  if constexpr (SHARED) { slot_base = row_tile * 128; rows = 128; B = Bg; }
  else {
    if (row_tile >= ntiles[0]) return;
    int4 d = desc[row_tile]; slot_base = d.y; rows = d.z;
    B = Bg + (size_t)d.x * DIM * INTER;
  }
  int n0 = col_tile * 128;
  int tid = threadIdx.x, lane = tid & 63;
  int wv = tid >> 6, wr = wv >> 1, wc = wv & 1;
  __shared__ u16 As[128][72];
  __shared__ u16 Bs[128][72];
  int ar = tid >> 3, ac = (tid & 7) * 8;
  const u16* asrc[4];
#pragma unroll
  for (int s = 0; s < 4; s++)
    asrc[s] = Hin + (size_t)(slot_base + s * 32 + ar) * KD + ac;
  int br = tid >> 4, bc = (tid & 15) * 4;
  const float* bp = B + (size_t)(n0 + br) * KD + bc;

  f32x4 acc[4][4];
#pragma unroll
  for (int m = 0; m < 4; m++)
#pragma unroll
    for (int n = 0; n < 4; n++) acc[m][n] = {0.f,0.f,0.f,0.f};

  for (int kk = 0; kk < KSTEPS; kk++) {
    __syncthreads();
#pragma unroll
    for (int s = 0; s < 4; s++) {
      uint4 v = *(const uint4*)(asrc[s] + kk * 64);
      *(uint4*)&As[s * 32 + ar][ac] = v;
    }
#pragma unroll
    for (int s = 0; s < 8; s++) {
      float4 v = *(const float4*)(bp + (size_t)(s * 16) * KD + kk * 64);
      union { u16 h[4]; uint2 q; } o;
      o.h[0] = f2bf(v.x); o.h[1] = f2bf(v.y); o.h[2] = f2bf(v.z); o.h[3] = f2bf(v.w);
      *(uint2*)&Bs[s * 16 + br][bc] = o.q;
    }
    __syncthreads();
#pragma unroll
    for (int h = 0; h < 2; h++) {
      bf16x8 af[4], bfv[4];
#pragma unroll
      for (int m = 0; m < 4; m++)
        af[m] = *(const bf16x8*)&As[wr * 64 + m * 16 + (lane & 15)][h * 32 + (lane >> 4) * 8];
#pragma unroll
      for (int n = 0; n < 4; n++)
        bfv[n] = *(const bf16x8*)&Bs[wc * 64 + n * 16 + (lane & 15)][h * 32 + (lane >> 4) * 8];
#pragma unroll
      for (int m = 0; m < 4; m++)
#pragma unroll
        for (int n = 0; n < 4; n++)
          acc[m][n] = __builtin_amdgcn_mfma_f32_16x16x32_bf16(af[m], bfv[n], acc[m][n], 0, 0, 0);
    }
  }
#pragma unroll
  for (int m = 0; m < 4; m++) {
#pragma unroll
    for (int r = 0; r < 4; r++) {
      int row_local = wr * 64 + m * 16 + (lane >> 4) * 4 + r;
      if (row_local < rows) {
        int slot = slot_base + row_local;
        size_t rp = (size_t)slot * DIM + n0 + wc * 64 + (lane & 15);
        if constexpr (SHARED) {
#pragma unroll
          for (int n = 0; n < 4; n++) yout[rp + n * 16] = acc[m][n][r];
        } else {
          float sw = pw[slot];
#pragma unroll
          for (int n = 0; n < 4; n++) slotout[rp + n * 16] = f2bf(acc[m][n][r] * sw);
        }
      }
    }
  }
}

// ---------------- final combine: y[t] = shared + sum_k slotout ----------------
__global__ __launch_bounds__(256)
void combine_k(float* __restrict__ y, const u16* __restrict__ slotout, const int* __restrict__ slotof)
{
  int t = blockIdx.x;
  int c = threadIdx.x * 8;
  size_t rp = (size_t)t * DIM + c;
  float4 a = *(const float4*)(y + rp);
  float4 b = *(const float4*)(y + rp + 4);
  float o[8] = {a.x, a.y, a.z, a.w, b.x, b.y, b.z, b.w};
#pragma unroll
  for (int k = 0; k < TOPK; k++) {
    int s = slotof[t * TOPK + k];
    uint4 v = *(const uint4*)(slotout + (size_t)s * DIM + c);
    o[0] += bf2f((u16)(v.x & 0xFFFFu)); o[1] += bf2f((u16)(v.x >> 16));
    o[2] += bf2f((u16)(v.y & 0xFFFFu)); o[3] += bf2f((u16)(v.y >> 16));
    o[4] += bf2f((u16)(v.z & 0xFFFFu)); o[5] += bf2f((u16)(v.z >> 16));
    o[6] += bf2f((u16)(v.w & 0xFFFFu)); o[7] += bf2f((u16)(v.w >> 16));
  }
  *(float4*)(y + rp)     = make_float4(o[0], o[1], o[2], o[3]);
  *(float4*)(y + rp + 4) = make_float4(o[4], o[5], o[6], o[7]);
}

// ---------------- host ----------------
extern "C" void kernel_launch(void* const* d_in, const int* in_sizes, int n_in,
                              void* d_out, int out_size, void* d_ws, size_t ws_size,
                              hipStream_t stream)
{
  const float* x   = (const float*)d_in[0];
  const float* gw  = (const float*)d_in[1];
  const float* w1  = (const float*)d_in[2];
  const float* w2  = (const float*)d_in[3];
  const float* w3  = (const float*)d_in[4];
  const float* sw1 = (const float*)d_in[5];
  const float* sw2 = (const float*)d_in[6];
  const float* sw3 = (const float*)d_in[7];
  float* y = (float*)d_out;
  char* ws = (char*)d_ws;

  int*   counts  = (int*)(ws + 0);
  int*   ntiles  = (int*)(ws + 256);
  int*   offs    = (int*)(ws + 512);
  int4*  desc128 = (int4*)(ws + 1024);
  int*   tidx    = (int*)(ws + 16384);
  float* tw      = (float*)(ws + 212992);
  int*   ptok    = (int*)(ws + 409600);
  float* pw      = (float*)(ws + 606208);
  int*   slotof  = (int*)(ws + 802816);
  u16*   xb      = (u16*)(ws + 1048576);
  u16*   H       = (u16*)(ws + 34603008ull);
  u16*   Hs      = (u16*)(ws + 173735936ull);
  u16*   sout    = (u16*)(ws + 219873280ull);
  u16*   w1b     = (u16*)(ws + 421199872ull);
  u16*   w3b     = (u16*)(ws + 605749248ull);
  u16*   w2b     = (u16*)(ws + 790298624ull);
  u16*   sw1b    = (u16*)(ws + 974848000ull);
  u16*   sw3b    = (u16*)(ws + 986382336ull);
  u16*   sw2b    = (u16*)(ws + 997916672ull);
  const unsigned long long NEED_FULL = 1009451008ull;

  zero32<<<1, 64, 0, stream>>>(counts);
  gate_route_k<<<2048, 256, 0, stream>>>(x, gw, tidx, tw, counts);
  cvt_w_k<<<2048, 256, 0, stream>>>(x, xb, T_TOK * DIM / 8);
  scan_desc_k<<<1, 64, 0, stream>>>(counts, offs, desc128, ntiles);
  perm_build_k<<<32, 1024, 0, stream>>>(tidx, tw, offs, ptok, pw, slotof);

  if (ws_size >= NEED_FULL) {
    const int NW = NEXP * INTER * DIM / 8;
    const int NS = SHINTER * DIM / 8;
    cvt_w_k<<<4096, 256, 0, stream>>>(w1,  w1b,  NW);
    cvt_w_k<<<4096, 256, 0, stream>>>(w3,  w3b,  NW);
    cvt_w_k<<<4096, 256, 0, stream>>>(w2,  w2b,  NW);
    cvt_w_k<<<1024, 256, 0, stream>>>(sw1, sw1b, NS);
    cvt_w_k<<<1024, 256, 0, stream>>>(sw3, sw3b, NS);
    cvt_w_k<<<1024, 256, 0, stream>>>(sw2, sw2b, NS);

    up2_k<false><<<dim3(416, 11), 256, 0, stream>>>(xb, w1b, w3b, ptok, desc128, ntiles, H);
    up2_k<true ><<<dim3(64, 22), 256, 0, stream>>>(xb, sw1b, sw3b, ptok, desc128, ntiles, Hs);
    down2_k<true ><<<dim3(64, 16), 256, 0, stream>>>(Hs, sw2b, desc128, ntiles, pw, sout, y);
    down2_k<false><<<dim3(416, 16), 256, 0, stream>>>(H, w2b, desc128, ntiles, pw, sout, y);
  } else {
    up_gemm_k<false><<<dim3(416, 11), 256, 0, stream>>>(xb, w1, w3, ptok, desc128, ntiles, H);
    up_gemm_k<true ><<<dim3(64, 22), 256, 0, stream>>>(xb, sw1, sw3, ptok, desc128, ntiles, Hs);
    down_gemm_k<true ><<<dim3(64, 16), 256, 0, stream>>>(Hs, sw2, desc128, ntiles, pw, sout, y);
    down_gemm_k<false><<<dim3(416, 16), 256, 0, stream>>>(H, w2, desc128, ntiles, pw, sout, y);
  }

  combine_k<<<8192, 256, 0, stream>>>(y, sout, slotof);
}

// Round 7
// 2139.495 us; speedup vs baseline: 1.7481x; 1.7481x over previous
//
#include <hip/hip_runtime.h>
#include <hip/hip_bf16.h>
#include <stdint.h>

typedef unsigned short u16;

#define T_TOK 8192
#define DIM 2048
#define INTER 1408
#define NEXP 32
#define TOPK 6
#define SHINTER 2816
#define SLOTS (T_TOK * TOPK)   // 49152

typedef __attribute__((ext_vector_type(8))) short bf16x8;
typedef __attribute__((ext_vector_type(4))) float f32x4;

__device__ inline u16 f2bf(float f) {
  union { float f; unsigned u; } c; c.f = f;
  unsigned r = (c.u + 0x7FFFu + ((c.u >> 16) & 1u)) >> 16;
  return (u16)r;
}
__device__ inline float bf2f(u16 h) {
  union { unsigned u; float f; } c; c.u = ((unsigned)h) << 16;
  return c.f;
}

__device__ __forceinline__ void gl16(const void* g, void* l) {
  __builtin_amdgcn_global_load_lds(
      (const __attribute__((address_space(1))) void*)g,
      (__attribute__((address_space(3))) void*)l, 16, 0, 0);
}

// ---------------- gate + routing ----------------
__global__ __launch_bounds__(256)
void gate_route_k(const float* __restrict__ x, const float* __restrict__ gw,
                  int* __restrict__ tidx, float* __restrict__ tw, int* __restrict__ counts)
{
  int lane = threadIdx.x & 63, w = threadIdx.x >> 6;
  int t = blockIdx.x * 4 + w;
  __shared__ float sc[4][32];
  __shared__ float gm[4][8];
  const float* xr = x + (size_t)t * DIM + lane * 4;
  float4 xv[8];
#pragma unroll
  for (int i = 0; i < 8; i++) xv[i] = *(const float4*)(xr + i * 256);
  for (int e = 0; e < NEXP; e++) {
    const float* g = gw + (size_t)e * DIM + lane * 4;
    float acc = 0.f;
#pragma unroll
    for (int i = 0; i < 8; i++) {
      float4 gv = *(const float4*)(g + i * 256);
      acc += xv[i].x * gv.x + xv[i].y * gv.y + xv[i].z * gv.z + xv[i].w * gv.w;
    }
#pragma unroll
    for (int off = 32; off > 0; off >>= 1) acc += __shfl_down(acc, off);
    if (lane == 0) sc[w][e] = 1.f / (1.f + __expf(-acc));
  }
  if (lane == 0) {
#pragma unroll
    for (int g = 0; g < 8; g++)
      gm[w][g] = fmaxf(fmaxf(sc[w][g*4+0], sc[w][g*4+1]), fmaxf(sc[w][g*4+2], sc[w][g*4+3]));
    unsigned gsel = 0u;
    for (int it = 0; it < 4; it++) {
      float best = -1.f; int bi = 0;
      for (int g = 0; g < 8; g++)
        if (!((gsel >> g) & 1u) && gm[w][g] > best) { best = gm[w][g]; bi = g; }
      gsel |= 1u << bi;
    }
    unsigned chosen = 0u; float wsum = 0.f;
    int ids[TOPK]; float wv[TOPK];
#pragma unroll
    for (int it = 0; it < TOPK; it++) {
      float best = -1.f; int bi = 0;
      for (int e = 0; e < NEXP; e++)
        if (((gsel >> (e >> 2)) & 1u) && !((chosen >> e) & 1u) && sc[w][e] > best) { best = sc[w][e]; bi = e; }
      chosen |= 1u << bi; ids[it] = bi; wv[it] = best; wsum += best;
    }
    float s = 2.5f / wsum;
#pragma unroll
    for (int k = 0; k < TOPK; k++) {
      tidx[t * TOPK + k] = ids[k];
      tw[t * TOPK + k] = wv[k] * s;
      atomicAdd(&counts[ids[k]], 1);
    }
  }
}

__global__ void zero32(int* p) { if (threadIdx.x < NEXP) p[threadIdx.x] = 0; }

// ---------------- scan + tile descriptors (single wave, shfl prefix) --------
__global__ void scan_desc_k(const int* __restrict__ counts, int* __restrict__ offs,
                            int4* __restrict__ desc128, int* __restrict__ ntiles)
{
  int lane = threadIdx.x;                      // 64 threads, one wave
  int c = (lane < NEXP) ? counts[lane] : 0;
  int inc = c;
#pragma unroll
  for (int d = 1; d < 64; d <<= 1) {
    int v = __shfl_up(inc, d);
    if (lane >= d) inc += v;
  }
  int off_e = inc - c;                          // exclusive
  int nt = (c + 127) >> 7;
  int tinc = nt;
#pragma unroll
  for (int d = 1; d < 64; d <<= 1) {
    int v = __shfl_up(tinc, d);
    if (lane >= d) tinc += v;
  }
  int tex = tinc - nt;
  if (lane < NEXP) {
    offs[lane] = off_e;
    for (int i = 0; i < nt; i++) {
      int rem = c - i * 128;
      desc128[tex + i] = make_int4(lane, off_e + i * 128, rem < 128 ? rem : 128, 0);
    }
  }
  if (lane == NEXP - 1) {
    offs[NEXP] = inc;
    ntiles[0] = tinc;
  }
}

// ---------------- deterministic permutation build ----------------
__global__ __launch_bounds__(1024)
void perm_build_k(const int* __restrict__ tidx, const float* __restrict__ tw,
                  const int* __restrict__ offs, int* __restrict__ ptok,
                  float* __restrict__ pw, int* __restrict__ slotof)
{
  int e = blockIdx.x;
  int tid = threadIdx.x, lane = tid & 63, w = tid >> 6;   // 16 waves
  __shared__ int wsum[16];
  __shared__ int cursor;
  if (tid == 0) cursor = offs[e];
  __syncthreads();
  for (int start = 0; start < SLOTS; start += 1024) {
    int i = start + tid;
    int match = (tidx[i] == e) ? 1 : 0;
    unsigned long long b = __ballot(match);
    if (lane == 0) wsum[w] = __popcll(b);
    __syncthreads();
    int base = cursor;
    int waveoff = 0;
    for (int ww = 0; ww < w; ww++) waveoff += wsum[ww];
    int total = 0;
#pragma unroll
    for (int ww = 0; ww < 16; ww++) total += wsum[ww];
    if (match) {
      int before = __popcll(b & ((1ull << lane) - 1ull));
      int slot = base + waveoff + before;
      ptok[slot] = i / TOPK;
      pw[slot] = tw[i];
      slotof[i] = slot;
    }
    __syncthreads();
    if (tid == 0) cursor = base + total;
  }
}

// ---------------- f32 -> bf16 conversion ----------------
__global__ __launch_bounds__(256)
void cvt_w_k(const float* __restrict__ src, u16* __restrict__ dst, int n8)
{
  int stride = gridDim.x * 256;
  for (size_t i = (size_t)blockIdx.x * 256 + threadIdx.x; i < (size_t)n8; i += stride) {
    size_t j = i * 8;
    float4 a = *(const float4*)(src + j);
    float4 b = *(const float4*)(src + j + 4);
    union { u16 h[8]; uint4 u; } p;
    p.h[0] = f2bf(a.x); p.h[1] = f2bf(a.y); p.h[2] = f2bf(a.z); p.h[3] = f2bf(a.w);
    p.h[4] = f2bf(b.x); p.h[5] = f2bf(b.y); p.h[6] = f2bf(b.z); p.h[7] = f2bf(b.w);
    *(uint4*)(dst + j) = p.u;
  }
}

// ============================================================================
// MAIN PATH (R2-verified engine + XCD swizzle; launch_bounds(256,2) — the
// (256,3) variant SPILLS the 128 accumulator registers, WRITE_SIZE 135MB->2.6GB,
// dur 703->2050us. Do not raise the occupancy bound on these kernels.)
// 128^2 tile, BK=64, all-gl16 staging, XOR-swizzled linear LDS, 2 barriers/step.
// ============================================================================

// fused up-GEMM: H = silu(X W1^T) * (X W3^T)
template<bool SHARED>
__global__ __launch_bounds__(256, 2)
void up2_k(const u16* __restrict__ xb,
           const u16* __restrict__ B1g, const u16* __restrict__ B3g,
           const int* __restrict__ ptok,
           const int4* __restrict__ desc, const int* __restrict__ ntiles,
           u16* __restrict__ Hout)
{
  constexpr int HLD = SHARED ? SHINTER : INTER;
  int rt0 = blockIdx.x;
  int row_tile = (rt0 & 7) * (int)(gridDim.x >> 3) + (rt0 >> 3);   // XCD swizzle
  int col_tile = blockIdx.y;
  int slot_base, rows;
  const u16 *B1, *B3;
  if constexpr (SHARED) { slot_base = row_tile * 128; rows = 128; B1 = B1g; B3 = B3g; }
  else {
    if (row_tile >= ntiles[0]) return;
    int4 d = desc[row_tile];
    slot_base = d.y; rows = d.z;
    size_t off = (size_t)d.x * (size_t)INTER * DIM;
    B1 = B1g + off; B3 = B3g + off;
  }
  int n0 = col_tile * 128;
  int tid = threadIdx.x, lane = tid & 63;
  int w = tid >> 6, wr = w >> 1, wc = w & 1;

  __shared__ u16 As[128][64];
  __shared__ u16 Bs1[128][64];
  __shared__ u16 Bs3[128][64];

  int selem = (((lane & 7) ^ (lane >> 3)) * 8);
  const u16 *a_src[4], *b1_src[4], *b3_src[4];
#pragma unroll
  for (int s = 0; s < 4; s++) {
    int r = w * 32 + s * 8 + (lane >> 3);
    int tok;
    if constexpr (SHARED) tok = slot_base + r;
    else { int rr = r < rows ? r : rows - 1; tok = ptok[slot_base + rr]; }
    a_src[s]  = xb + (size_t)tok * DIM + selem;
    b1_src[s] = B1 + (size_t)(n0 + r) * DIM + selem;
    b3_src[s] = B3 + (size_t)(n0 + r) * DIM + selem;
  }

  f32x4 acc1[4][4], acc3[4][4];
#pragma unroll
  for (int m = 0; m < 4; m++)
#pragma unroll
    for (int n = 0; n < 4; n++) { acc1[m][n] = {0.f,0.f,0.f,0.f}; acc3[m][n] = {0.f,0.f,0.f,0.f}; }

  for (int kk = 0; kk < DIM / 64; kk++) {
    __syncthreads();
#pragma unroll
    for (int s = 0; s < 4; s++) {
      gl16(a_src[s]  + kk * 64, &As [w * 32 + s * 8][0]);
      gl16(b1_src[s] + kk * 64, &Bs1[w * 32 + s * 8][0]);
      gl16(b3_src[s] + kk * 64, &Bs3[w * 32 + s * 8][0]);
    }
    __syncthreads();
#pragma unroll
    for (int h = 0; h < 2; h++) {
      bf16x8 af[4], b1f[4], b3f[4];
      int chk = (h * 4 + (lane >> 4)) ^ (lane & 7);
#pragma unroll
      for (int m = 0; m < 4; m++)
        af[m] = *(const bf16x8*)&As[wr * 64 + m * 16 + (lane & 15)][chk * 8];
#pragma unroll
      for (int n = 0; n < 4; n++) {
        b1f[n] = *(const bf16x8*)&Bs1[wc * 64 + n * 16 + (lane & 15)][chk * 8];
        b3f[n] = *(const bf16x8*)&Bs3[wc * 64 + n * 16 + (lane & 15)][chk * 8];
      }
#pragma unroll
      for (int m = 0; m < 4; m++)
#pragma unroll
        for (int n = 0; n < 4; n++) {
          acc1[m][n] = __builtin_amdgcn_mfma_f32_16x16x32_bf16(af[m], b1f[n], acc1[m][n], 0, 0, 0);
          acc3[m][n] = __builtin_amdgcn_mfma_f32_16x16x32_bf16(af[m], b3f[n], acc3[m][n], 0, 0, 0);
        }
    }
  }
#pragma unroll
  for (int m = 0; m < 4; m++) {
#pragma unroll
    for (int r = 0; r < 4; r++) {
      int row_local = wr * 64 + m * 16 + (lane >> 4) * 4 + r;
      if (row_local < rows) {
        size_t rowp = (size_t)(slot_base + row_local) * HLD + n0 + wc * 64 + (lane & 15);
#pragma unroll
        for (int n = 0; n < 4; n++) {
          float c1 = acc1[m][n][r], c3 = acc3[m][n][r];
          float hval = (c1 / (1.f + __expf(-c1))) * c3;
          Hout[rowp + n * 16] = f2bf(hval);
        }
      }
    }
  }
}

// down-GEMM: O = H W2^T (+route-weight scale for routed path)
template<bool SHARED>
__global__ __launch_bounds__(256, 2)
void down2_k(const u16* __restrict__ Hin, const u16* __restrict__ Bg,
             const int4* __restrict__ desc, const int* __restrict__ ntiles,
             const float* __restrict__ pw,
             u16* __restrict__ slotout, float* __restrict__ yout)
{
  constexpr int KD = SHARED ? SHINTER : INTER;
  constexpr int KSTEPS = KD / 64;
  int rt0 = blockIdx.x;
  int row_tile = (rt0 & 7) * (int)(gridDim.x >> 3) + (rt0 >> 3);   // XCD swizzle
  int col_tile = blockIdx.y;
  int slot_base, rows; const u16* B;
  if constexpr (SHARED) { slot_base = row_tile * 128; rows = 128; B = Bg; }
  else {
    if (row_tile >= ntiles[0]) return;
    int4 d = desc[row_tile]; slot_base = d.y; rows = d.z;
    B = Bg + (size_t)d.x * DIM * INTER;
  }
  int n0 = col_tile * 128;
  int tid = threadIdx.x, lane = tid & 63;
  int w = tid >> 6, wr = w >> 1, wc = w & 1;
  __shared__ u16 As[128][64];
  __shared__ u16 Bs[128][64];

  int selem = (((lane & 7) ^ (lane >> 3)) * 8);
  const u16 *a_src[4], *b_src[4];
#pragma unroll
  for (int s = 0; s < 4; s++) {
    int r = w * 32 + s * 8 + (lane >> 3);
    a_src[s] = Hin + (size_t)(slot_base + r) * KD + selem;
    b_src[s] = B + (size_t)(n0 + r) * KD + selem;
  }

  f32x4 acc[4][4];
#pragma unroll
  for (int m = 0; m < 4; m++)
#pragma unroll
    for (int n = 0; n < 4; n++) acc[m][n] = {0.f,0.f,0.f,0.f};

  for (int kk = 0; kk < KSTEPS; kk++) {
    __syncthreads();
#pragma unroll
    for (int s = 0; s < 4; s++) {
      gl16(a_src[s] + kk * 64, &As[w * 32 + s * 8][0]);
      gl16(b_src[s] + kk * 64, &Bs[w * 32 + s * 8][0]);
    }
    __syncthreads();
#pragma unroll
    for (int h = 0; h < 2; h++) {
      bf16x8 af[4], bfv[4];
      int chk = (h * 4 + (lane >> 4)) ^ (lane & 7);
#pragma unroll
      for (int m = 0; m < 4; m++)
        af[m] = *(const bf16x8*)&As[wr * 64 + m * 16 + (lane & 15)][chk * 8];
#pragma unroll
      for (int n = 0; n < 4; n++)
        bfv[n] = *(const bf16x8*)&Bs[wc * 64 + n * 16 + (lane & 15)][chk * 8];
#pragma unroll
      for (int m = 0; m < 4; m++)
#pragma unroll
        for (int n = 0; n < 4; n++)
          acc[m][n] = __builtin_amdgcn_mfma_f32_16x16x32_bf16(af[m], bfv[n], acc[m][n], 0, 0, 0);
    }
  }
#pragma unroll
  for (int m = 0; m < 4; m++) {
#pragma unroll
    for (int r = 0; r < 4; r++) {
      int row_local = wr * 64 + m * 16 + (lane >> 4) * 4 + r;
      if (row_local < rows) {
        int slot = slot_base + row_local;
        size_t rp = (size_t)slot * DIM + n0 + wc * 64 + (lane & 15);
        if constexpr (SHARED) {
#pragma unroll
          for (int n = 0; n < 4; n++) yout[rp + n * 16] = acc[m][n][r];
        } else {
          float sw = pw[slot];
#pragma unroll
          for (int n = 0; n < 4; n++) slotout[rp + n * 16] = f2bf(acc[m][n][r] * sw);
        }
      }
    }
  }
}

// ============================================================================
// FALLBACK PATH (f32 weights, 128^2 reg-staged) — used only if ws too small
// ============================================================================
template<bool SHARED>
__global__ __launch_bounds__(256, 2)
void up_gemm_k(const u16* __restrict__ xb,
               const float* __restrict__ W1g, const float* __restrict__ W3g,
               const int* __restrict__ ptok,
               const int4* __restrict__ desc, const int* __restrict__ ntiles,
               u16* __restrict__ Hout)
{
  constexpr int HLD = SHARED ? SHINTER : INTER;
  int row_tile = blockIdx.x, col_tile = blockIdx.y;
  int slot_base, rows;
  const float *B1, *B3;
  if constexpr (SHARED) {
    slot_base = row_tile * 128; rows = 128; B1 = W1g; B3 = W3g;
  } else {
    if (row_tile >= ntiles[0]) return;
    int4 d = desc[row_tile];
    slot_base = d.y; rows = d.z;
    size_t off = (size_t)d.x * (size_t)INTER * DIM;
    B1 = W1g + off; B3 = W3g + off;
  }
  int n0 = col_tile * 128;
  int tid = threadIdx.x, lane = tid & 63;
  int wv = tid >> 6, wr = wv >> 1, wc = wv & 1;

  __shared__ u16 As[128][72];
  __shared__ u16 Bs1[128][72];
  __shared__ u16 Bs3[128][72];

  int ar = tid >> 3, ac = (tid & 7) * 8;
  const u16* asrc[4];
#pragma unroll
  for (int s = 0; s < 4; s++) {
    int r = s * 32 + ar;
    int tok;
    if constexpr (SHARED) tok = slot_base + r;
    else { int rr = r < rows ? r : rows - 1; tok = ptok[slot_base + rr]; }
    asrc[s] = xb + (size_t)tok * DIM + ac;
  }
  int br = tid >> 4, bc = (tid & 15) * 4;
  const float* b1p = B1 + (size_t)(n0 + br) * DIM + bc;
  const float* b3p = B3 + (size_t)(n0 + br) * DIM + bc;

  f32x4 acc1[4][4], acc3[4][4];
#pragma unroll
  for (int m = 0; m < 4; m++)
#pragma unroll
    for (int n = 0; n < 4; n++) { acc1[m][n] = {0.f,0.f,0.f,0.f}; acc3[m][n] = {0.f,0.f,0.f,0.f}; }

  for (int kk = 0; kk < DIM / 64; kk++) {
    __syncthreads();
#pragma unroll
    for (int s = 0; s < 4; s++) {
      uint4 v = *(const uint4*)(asrc[s] + kk * 64);
      *(uint4*)&As[s * 32 + ar][ac] = v;
    }
#pragma unroll
    for (int s = 0; s < 8; s++) {
      float4 v = *(const float4*)(b1p + (size_t)(s * 16) * DIM + kk * 64);
      union { u16 h[4]; uint2 q; } o;
      o.h[0] = f2bf(v.x); o.h[1] = f2bf(v.y); o.h[2] = f2bf(v.z); o.h[3] = f2bf(v.w);
      *(uint2*)&Bs1[s * 16 + br][bc] = o.q;
    }
#pragma unroll
    for (int s = 0; s < 8; s++) {
      float4 v = *(const float4*)(b3p + (size_t)(s * 16) * DIM + kk * 64);
      union { u16 h[4]; uint2 q; } o;
      o.h[0] = f2bf(v.x); o.h[1] = f2bf(v.y); o.h[2] = f2bf(v.z); o.h[3] = f2bf(v.w);
      *(uint2*)&Bs3[s * 16 + br][bc] = o.q;
    }
    __syncthreads();
#pragma unroll
    for (int h = 0; h < 2; h++) {
      bf16x8 af[4], b1f[4], b3f[4];
#pragma unroll
      for (int m = 0; m < 4; m++)
        af[m] = *(const bf16x8*)&As[wr * 64 + m * 16 + (lane & 15)][h * 32 + (lane >> 4) * 8];
#pragma unroll
      for (int n = 0; n < 4; n++) {
        b1f[n] = *(const bf16x8*)&Bs1[wc * 64 + n * 16 + (lane & 15)][h * 32 + (lane >> 4) * 8];
        b3f[n] = *(const bf16x8*)&Bs3[wc * 64 + n * 16 + (lane & 15)][h * 32 + (lane >> 4) * 8];
      }
#pragma unroll
      for (int m = 0; m < 4; m++)
#pragma unroll
        for (int n = 0; n < 4; n++) {
          acc1[m][n] = __builtin_amdgcn_mfma_f32_16x16x32_bf16(af[m], b1f[n], acc1[m][n], 0, 0, 0);
          acc3[m][n] = __builtin_amdgcn_mfma_f32_16x16x32_bf16(af[m], b3f[n], acc3[m][n], 0, 0, 0);
        }
    }
  }
#pragma unroll
  for (int m = 0; m < 4; m++) {
#pragma unroll
    for (int r = 0; r < 4; r++) {
      int row_local = wr * 64 + m * 16 + (lane >> 4) * 4 + r;
      if (row_local < rows) {
        size_t rowp = (size_t)(slot_base + row_local) * HLD + n0 + wc * 64 + (lane & 15);
#pragma unroll
        for (int n = 0; n < 4; n++) {
          float c1 = acc1[m][n][r], c3 = acc3[m][n][r];
          float hval = (c1 / (1.f + __expf(-c1))) * c3;
          Hout[rowp + n * 16] = f2bf(hval);
        }
      }
    }
  }
}

template<bool SHARED>
__global__ __launch_bounds__(256, 2)
void down_gemm_k(const u16* __restrict__ Hin, const float* __restrict__ Bg,
                 const int4* __restrict__ desc, const int* __restrict__ ntiles,
                 const float* __restrict__ pw,
                 u16* __restrict__ slotout, float* __restrict__ yout)
{
  constexpr int KD = SHARED ? SHINTER : INTER;
  constexpr int KSTEPS = KD / 64;
  int row_tile = blockIdx.x, col_tile = blockIdx.y;
  int slot_base, rows; const float* B;
  if constexpr (SHARED) { slot_base = row_tile * 128; rows = 128; B = Bg; }
  else {
    if (row_tile >= ntiles[0]) return;
    int4 d = desc[row_tile]; slot_base = d.y; rows = d.z;
    B = Bg + (size_t)d.x * DIM * INTER;
  }
  int n0 = col_tile * 128;
  int tid = threadIdx.x, lane = tid & 63;
  int wv = tid >> 6, wr = wv >> 1, wc = wv & 1;
  __shared__ u16 As[128][72];
  __shared__ u16 Bs[128][72];
  int ar = tid >> 3, ac = (tid & 7) * 8;
  const u16* asrc[4];
#pragma unroll
  for (int s = 0; s < 4; s++)
    asrc[s] = Hin + (size_t)(slot_base + s * 32 + ar) * KD + ac;
  int br = tid >> 4, bc = (tid & 15) * 4;
  const float* bp = B + (size_t)(n0 + br) * KD + bc;

  f32x4 acc[4][4];
#pragma unroll
  for (int m = 0; m < 4; m++)
#pragma unroll
    for (int n = 0; n < 4; n++) acc[m][n] = {0.f,0.f,0.f,0.f};

  for (int kk = 0; kk < KSTEPS; kk++) {
    __syncthreads();
#pragma unroll
    for (int s = 0; s < 4; s++) {
      uint4 v = *(const uint4*)(asrc[s] + kk * 64);
      *(uint4*)&As[s * 32 + ar][ac] = v;
    }
#pragma unroll
    for (int s = 0; s < 8; s++) {
      float4 v = *(const float4*)(bp + (size_t)(s * 16) * KD + kk * 64);
      union { u16 h[4]; uint2 q; } o;
      o.h[0] = f2bf(v.x); o.h[1] = f2bf(v.y); o.h[2] = f2bf(v.z); o.h[3] = f2bf(v.w);
      *(uint2*)&Bs[s * 16 + br][bc] = o.q;
    }
    __syncthreads();
#pragma unroll
    for (int h = 0; h < 2; h++) {
      bf16x8 af[4], bfv[4];
#pragma unroll
      for (int m = 0; m < 4; m++)
        af[m] = *(const bf16x8*)&As[wr * 64 + m * 16 + (lane & 15)][h * 32 + (lane >> 4) * 8];
#pragma unroll
      for (int n = 0; n < 4; n++)
        bfv[n] = *(const bf16x8*)&Bs[wc * 64 + n * 16 + (lane & 15)][h * 32 + (lane >> 4) * 8];
#pragma unroll
      for (int m = 0; m < 4; m++)
#pragma unroll
        for (int n = 0; n < 4; n++)
          acc[m][n] = __builtin_amdgcn_mfma_f32_16x16x32_bf16(af[m], bfv[n], acc[m][n], 0, 0, 0);
    }
  }
#pragma unroll
  for (int m = 0; m < 4; m++) {
#pragma unroll
    for (int r = 0; r < 4; r++) {
      int row_local = wr * 64 + m * 16 + (lane >> 4) * 4 + r;
      if (row_local < rows) {
        int slot = slot_base + row_local;
        size_t rp = (size_t)slot * DIM + n0 + wc * 64 + (lane & 15);
        if constexpr (SHARED) {
#pragma unroll
          for (int n = 0; n < 4; n++) yout[rp + n * 16] = acc[m][n][r];
        } else {
          float sw = pw[slot];
#pragma unroll
          for (int n = 0; n < 4; n++) slotout[rp + n * 16] = f2bf(acc[m][n][r] * sw);
        }
      }
    }
  }
}

// ---------------- final combine: y[t] = shared + sum_k slotout ----------------
__global__ __launch_bounds__(256)
void combine_k(float* __restrict__ y, const u16* __restrict__ slotout, const int* __restrict__ slotof)
{
  int t = blockIdx.x;
  int c = threadIdx.x * 8;
  size_t rp = (size_t)t * DIM + c;
  float4 a = *(const float4*)(y + rp);
  float4 b = *(const float4*)(y + rp + 4);
  float o[8] = {a.x, a.y, a.z, a.w, b.x, b.y, b.z, b.w};
#pragma unroll
  for (int k = 0; k < TOPK; k++) {
    int s = slotof[t * TOPK + k];
    uint4 v = *(const uint4*)(slotout + (size_t)s * DIM + c);
    o[0] += bf2f((u16)(v.x & 0xFFFFu)); o[1] += bf2f((u16)(v.x >> 16));
    o[2] += bf2f((u16)(v.y & 0xFFFFu)); o[3] += bf2f((u16)(v.y >> 16));
    o[4] += bf2f((u16)(v.z & 0xFFFFu)); o[5] += bf2f((u16)(v.z >> 16));
    o[6] += bf2f((u16)(v.w & 0xFFFFu)); o[7] += bf2f((u16)(v.w >> 16));
  }
  *(float4*)(y + rp)     = make_float4(o[0], o[1], o[2], o[3]);
  *(float4*)(y + rp + 4) = make_float4(o[4], o[5], o[6], o[7]);
}

// ---------------- host ----------------
extern "C" void kernel_launch(void* const* d_in, const int* in_sizes, int n_in,
                              void* d_out, int out_size, void* d_ws, size_t ws_size,
                              hipStream_t stream)
{
  const float* x   = (const float*)d_in[0];
  const float* gw  = (const float*)d_in[1];
  const float* w1  = (const float*)d_in[2];
  const float* w2  = (const float*)d_in[3];
  const float* w3  = (const float*)d_in[4];
  const float* sw1 = (const float*)d_in[5];
  const float* sw2 = (const float*)d_in[6];
  const float* sw3 = (const float*)d_in[7];
  float* y = (float*)d_out;
  char* ws = (char*)d_ws;

  int*   counts  = (int*)(ws + 0);
  int*   ntiles  = (int*)(ws + 256);
  int*   offs    = (int*)(ws + 512);
  int4*  desc128 = (int4*)(ws + 1024);
  int*   tidx    = (int*)(ws + 16384);
  float* tw      = (float*)(ws + 212992);
  int*   ptok    = (int*)(ws + 409600);
  float* pw      = (float*)(ws + 606208);
  int*   slotof  = (int*)(ws + 802816);
  u16*   xb      = (u16*)(ws + 1048576);
  u16*   H       = (u16*)(ws + 34603008ull);
  u16*   Hs      = (u16*)(ws + 173735936ull);
  u16*   sout    = (u16*)(ws + 219873280ull);
  u16*   w1b     = (u16*)(ws + 421199872ull);
  u16*   w3b     = (u16*)(ws + 605749248ull);
  u16*   w2b     = (u16*)(ws + 790298624ull);
  u16*   sw1b    = (u16*)(ws + 974848000ull);
  u16*   sw3b    = (u16*)(ws + 986382336ull);
  u16*   sw2b    = (u16*)(ws + 997916672ull);
  const unsigned long long NEED_FULL = 1009451008ull;

  zero32<<<1, 64, 0, stream>>>(counts);
  gate_route_k<<<2048, 256, 0, stream>>>(x, gw, tidx, tw, counts);
  cvt_w_k<<<2048, 256, 0, stream>>>(x, xb, T_TOK * DIM / 8);
  scan_desc_k<<<1, 64, 0, stream>>>(counts, offs, desc128, ntiles);
  perm_build_k<<<32, 1024, 0, stream>>>(tidx, tw, offs, ptok, pw, slotof);

  if (ws_size >= NEED_FULL) {
    const int NW = NEXP * INTER * DIM / 8;
    const int NS = SHINTER * DIM / 8;
    cvt_w_k<<<4096, 256, 0, stream>>>(w1,  w1b,  NW);
    cvt_w_k<<<4096, 256, 0, stream>>>(w3,  w3b,  NW);
    cvt_w_k<<<4096, 256, 0, stream>>>(w2,  w2b,  NW);
    cvt_w_k<<<1024, 256, 0, stream>>>(sw1, sw1b, NS);
    cvt_w_k<<<1024, 256, 0, stream>>>(sw3, sw3b, NS);
    cvt_w_k<<<1024, 256, 0, stream>>>(sw2, sw2b, NS);

    up2_k<false><<<dim3(416, 11), 256, 0, stream>>>(xb, w1b, w3b, ptok, desc128, ntiles, H);
    up2_k<true ><<<dim3(64, 22), 256, 0, stream>>>(xb, sw1b, sw3b, ptok, desc128, ntiles, Hs);
    down2_k<true ><<<dim3(64, 16), 256, 0, stream>>>(Hs, sw2b, desc128, ntiles, pw, sout, y);
    down2_k<false><<<dim3(416, 16), 256, 0, stream>>>(H, w2b, desc128, ntiles, pw, sout, y);
  } else {
    up_gemm_k<false><<<dim3(416, 11), 256, 0, stream>>>(xb, w1, w3, ptok, desc128, ntiles, H);
    up_gemm_k<true ><<<dim3(64, 22), 256, 0, stream>>>(xb, sw1, sw3, ptok, desc128, ntiles, Hs);
    down_gemm_k<true ><<<dim3(64, 16), 256, 0, stream>>>(Hs, sw2, desc128, ntiles, pw, sout, y);
    down_gemm_k<false><<<dim3(416, 16), 256, 0, stream>>>(H, w2, desc128, ntiles, pw, sout, y);
  }

  combine_k<<<8192, 256, 0, stream>>>(y, sout, slotof);
}

// Round 8
// 2056.965 us; speedup vs baseline: 1.8182x; 1.0401x over previous
//
#include <hip/hip_runtime.h>
#include <hip/hip_bf16.h>
#include <stdint.h>

typedef unsigned short u16;

#define T_TOK 8192
#define DIM 2048
#define INTER 1408
#define NEXP 32
#define TOPK 6
#define SHINTER 2816
#define SLOTS (T_TOK * TOPK)   // 49152

typedef __attribute__((ext_vector_type(8))) short bf16x8;
typedef __attribute__((ext_vector_type(4))) float f32x4;

__device__ inline u16 f2bf(float f) {
  union { float f; unsigned u; } c; c.f = f;
  unsigned r = (c.u + 0x7FFFu + ((c.u >> 16) & 1u)) >> 16;
  return (u16)r;
}
__device__ inline float bf2f(u16 h) {
  union { unsigned u; float f; } c; c.u = ((unsigned)h) << 16;
  return c.f;
}

__device__ __forceinline__ void gl16(const void* g, void* l) {
  __builtin_amdgcn_global_load_lds(
      (const __attribute__((address_space(1))) void*)g,
      (__attribute__((address_space(3))) void*)l, 16, 0, 0);
}

// ---------------- gate + routing (+ fused x->bf16) ----------------
__global__ __launch_bounds__(256)
void gate_route_k(const float* __restrict__ x, const float* __restrict__ gw,
                  int* __restrict__ tidx, float* __restrict__ tw,
                  int* __restrict__ counts, u16* __restrict__ xb)
{
  int lane = threadIdx.x & 63, w = threadIdx.x >> 6;
  int t = blockIdx.x * 4 + w;
  __shared__ float sc[4][32];
  __shared__ float gm[4][8];
  const float* xr = x + (size_t)t * DIM + lane * 4;
  float4 xv[8];
#pragma unroll
  for (int i = 0; i < 8; i++) xv[i] = *(const float4*)(xr + i * 256);
  // fused x -> bf16 (row is already in registers)
  u16* xrow = xb + (size_t)t * DIM + lane * 4;
#pragma unroll
  for (int i = 0; i < 8; i++) {
    union { u16 h[4]; uint2 q; } p;
    p.h[0] = f2bf(xv[i].x); p.h[1] = f2bf(xv[i].y);
    p.h[2] = f2bf(xv[i].z); p.h[3] = f2bf(xv[i].w);
    *(uint2*)(xrow + i * 256) = p.q;
  }
  for (int e = 0; e < NEXP; e++) {
    const float* g = gw + (size_t)e * DIM + lane * 4;
    float acc = 0.f;
#pragma unroll
    for (int i = 0; i < 8; i++) {
      float4 gv = *(const float4*)(g + i * 256);
      acc += xv[i].x * gv.x + xv[i].y * gv.y + xv[i].z * gv.z + xv[i].w * gv.w;
    }
#pragma unroll
    for (int off = 32; off > 0; off >>= 1) acc += __shfl_down(acc, off);
    if (lane == 0) sc[w][e] = 1.f / (1.f + __expf(-acc));
  }
  if (lane == 0) {
#pragma unroll
    for (int g = 0; g < 8; g++)
      gm[w][g] = fmaxf(fmaxf(sc[w][g*4+0], sc[w][g*4+1]), fmaxf(sc[w][g*4+2], sc[w][g*4+3]));
    unsigned gsel = 0u;
    for (int it = 0; it < 4; it++) {
      float best = -1.f; int bi = 0;
      for (int g = 0; g < 8; g++)
        if (!((gsel >> g) & 1u) && gm[w][g] > best) { best = gm[w][g]; bi = g; }
      gsel |= 1u << bi;
    }
    unsigned chosen = 0u; float wsum = 0.f;
    int ids[TOPK]; float wv[TOPK];
#pragma unroll
    for (int it = 0; it < TOPK; it++) {
      float best = -1.f; int bi = 0;
      for (int e = 0; e < NEXP; e++)
        if (((gsel >> (e >> 2)) & 1u) && !((chosen >> e) & 1u) && sc[w][e] > best) { best = sc[w][e]; bi = e; }
      chosen |= 1u << bi; ids[it] = bi; wv[it] = best; wsum += best;
    }
    float s = 2.5f / wsum;
#pragma unroll
    for (int k = 0; k < TOPK; k++) {
      tidx[t * TOPK + k] = ids[k];
      tw[t * TOPK + k] = wv[k] * s;
      atomicAdd(&counts[ids[k]], 1);
    }
  }
}

__global__ void zero32(int* p) { if (threadIdx.x < NEXP) p[threadIdx.x] = 0; }

// ---------------- scan + tile descriptors (single wave, shfl prefix) --------
__global__ void scan_desc_k(const int* __restrict__ counts, int* __restrict__ offs,
                            int4* __restrict__ desc128, int* __restrict__ ntiles)
{
  int lane = threadIdx.x;                      // 64 threads, one wave
  int c = (lane < NEXP) ? counts[lane] : 0;
  int inc = c;
#pragma unroll
  for (int d = 1; d < 64; d <<= 1) {
    int v = __shfl_up(inc, d);
    if (lane >= d) inc += v;
  }
  int off_e = inc - c;                          // exclusive
  int nt = (c + 127) >> 7;
  int tinc = nt;
#pragma unroll
  for (int d = 1; d < 64; d <<= 1) {
    int v = __shfl_up(tinc, d);
    if (lane >= d) tinc += v;
  }
  int tex = tinc - nt;
  if (lane < NEXP) {
    offs[lane] = off_e;
    for (int i = 0; i < nt; i++) {
      int rem = c - i * 128;
      desc128[tex + i] = make_int4(lane, off_e + i * 128, rem < 128 ? rem : 128, 0);
    }
  }
  if (lane == NEXP - 1) {
    offs[NEXP] = inc;
    ntiles[0] = tinc;
  }
}

// ---------------- deterministic permutation build ----------------
__global__ __launch_bounds__(1024)
void perm_build_k(const int* __restrict__ tidx, const float* __restrict__ tw,
                  const int* __restrict__ offs, int* __restrict__ ptok,
                  float* __restrict__ pw, int* __restrict__ slotof)
{
  int e = blockIdx.x;
  int tid = threadIdx.x, lane = tid & 63, w = tid >> 6;   // 16 waves
  __shared__ int wsum[16];
  __shared__ int cursor;
  if (tid == 0) cursor = offs[e];
  __syncthreads();
  for (int start = 0; start < SLOTS; start += 1024) {
    int i = start + tid;
    int match = (tidx[i] == e) ? 1 : 0;
    unsigned long long b = __ballot(match);
    if (lane == 0) wsum[w] = __popcll(b);
    __syncthreads();
    int base = cursor;
    int waveoff = 0;
    for (int ww = 0; ww < w; ww++) waveoff += wsum[ww];
    int total = 0;
#pragma unroll
    for (int ww = 0; ww < 16; ww++) total += wsum[ww];
    if (match) {
      int before = __popcll(b & ((1ull << lane) - 1ull));
      int slot = base + waveoff + before;
      ptok[slot] = i / TOPK;
      pw[slot] = tw[i];
      slotof[i] = slot;
    }
    __syncthreads();
    if (tid == 0) cursor = base + total;
  }
}

// ---------------- f32 -> bf16 conversion, 3 tensors per launch ----------------
__global__ __launch_bounds__(256)
void cvt3_k(const float* __restrict__ s0, const float* __restrict__ s1,
            const float* __restrict__ s2, u16* __restrict__ d0,
            u16* __restrict__ d1, u16* __restrict__ d2, int n8)
{
  const float* src = (blockIdx.y == 0) ? s0 : (blockIdx.y == 1) ? s1 : s2;
  u16*         dst = (blockIdx.y == 0) ? d0 : (blockIdx.y == 1) ? d1 : d2;
  int stride = gridDim.x * 256;
  for (size_t i = (size_t)blockIdx.x * 256 + threadIdx.x; i < (size_t)n8; i += stride) {
    size_t j = i * 8;
    float4 a = *(const float4*)(src + j);
    float4 b = *(const float4*)(src + j + 4);
    union { u16 h[8]; uint4 u; } p;
    p.h[0] = f2bf(a.x); p.h[1] = f2bf(a.y); p.h[2] = f2bf(a.z); p.h[3] = f2bf(a.w);
    p.h[4] = f2bf(b.x); p.h[5] = f2bf(b.y); p.h[6] = f2bf(b.z); p.h[7] = f2bf(b.w);
    *(uint4*)(dst + j) = p.u;
  }
}

// ============================================================================
// MAIN GEMMs (R7-verified engine, frozen): 128^2 tile, BK=64, all-gl16 staging,
// XOR-swizzled linear LDS, 2 barriers/step, launch_bounds(256,2).
// (256,3) SPILLS the 128 accumulator regs (WRITE_SIZE 135MB->2.6GB) — keep 2.
// This round: routed+shared merged into ONE launch via flat 1D grid; segment
// bases divisible by 8 so the XCD swizzle ((rt0&7)*chunk + rt0>>3) still maps
// contiguous same-expert tiles to one XCD's L2.
// ============================================================================

#define UP_RSEG (416 * 11)     // routed up blocks
#define DN_RSEG (416 * 16)     // routed down blocks

// fused up-GEMM: H(s) = silu(X W1^T) * (X W3^T), routed + shared in one grid
__global__ __launch_bounds__(256, 2)
void up2m_k(const u16* __restrict__ xb,
            const u16* __restrict__ w1b, const u16* __restrict__ w3b,
            const u16* __restrict__ sw1b, const u16* __restrict__ sw3b,
            const int* __restrict__ ptok,
            const int4* __restrict__ desc, const int* __restrict__ ntiles,
            u16* __restrict__ H, u16* __restrict__ Hs)
{
  int bid = blockIdx.x;
  bool routed = bid < UP_RSEG;
  int slot_base, rows, n0, hld;
  const u16 *B1, *B3;
  u16* out;
  bool gather;
  if (routed) {
    int rt0 = bid % 416, ct = bid / 416;
    int rt = (rt0 & 7) * 52 + (rt0 >> 3);        // 416/8 = 52, bijective
    if (rt >= ntiles[0]) return;
    int4 d = desc[rt];
    slot_base = d.y; rows = d.z;
    size_t off = (size_t)d.x * (size_t)INTER * DIM;
    B1 = w1b + off; B3 = w3b + off;
    n0 = ct * 128; hld = INTER; out = H; gather = true;
  } else {
    int b2 = bid - UP_RSEG;
    int rt0 = b2 & 63, ct = b2 >> 6;             // 64 row tiles, 22 col tiles
    int rt = (rt0 & 7) * 8 + (rt0 >> 3);
    slot_base = rt * 128; rows = 128;
    B1 = sw1b; B3 = sw3b;
    n0 = ct * 128; hld = SHINTER; out = Hs; gather = false;
  }
  int tid = threadIdx.x, lane = tid & 63;
  int w = tid >> 6, wr = w >> 1, wc = w & 1;

  __shared__ u16 As[128][64];
  __shared__ u16 Bs1[128][64];
  __shared__ u16 Bs3[128][64];

  int selem = (((lane & 7) ^ (lane >> 3)) * 8);
  const u16 *a_src[4], *b1_src[4], *b3_src[4];
#pragma unroll
  for (int s = 0; s < 4; s++) {
    int r = w * 32 + s * 8 + (lane >> 3);
    int tok;
    if (gather) { int rr = r < rows ? r : rows - 1; tok = ptok[slot_base + rr]; }
    else tok = slot_base + r;
    a_src[s]  = xb + (size_t)tok * DIM + selem;
    b1_src[s] = B1 + (size_t)(n0 + r) * DIM + selem;
    b3_src[s] = B3 + (size_t)(n0 + r) * DIM + selem;
  }

  f32x4 acc1[4][4], acc3[4][4];
#pragma unroll
  for (int m = 0; m < 4; m++)
#pragma unroll
    for (int n = 0; n < 4; n++) { acc1[m][n] = {0.f,0.f,0.f,0.f}; acc3[m][n] = {0.f,0.f,0.f,0.f}; }

  for (int kk = 0; kk < DIM / 64; kk++) {
    __syncthreads();
#pragma unroll
    for (int s = 0; s < 4; s++) {
      gl16(a_src[s]  + kk * 64, &As [w * 32 + s * 8][0]);
      gl16(b1_src[s] + kk * 64, &Bs1[w * 32 + s * 8][0]);
      gl16(b3_src[s] + kk * 64, &Bs3[w * 32 + s * 8][0]);
    }
    __syncthreads();
#pragma unroll
    for (int h = 0; h < 2; h++) {
      bf16x8 af[4], b1f[4], b3f[4];
      int chk = (h * 4 + (lane >> 4)) ^ (lane & 7);
#pragma unroll
      for (int m = 0; m < 4; m++)
        af[m] = *(const bf16x8*)&As[wr * 64 + m * 16 + (lane & 15)][chk * 8];
#pragma unroll
      for (int n = 0; n < 4; n++) {
        b1f[n] = *(const bf16x8*)&Bs1[wc * 64 + n * 16 + (lane & 15)][chk * 8];
        b3f[n] = *(const bf16x8*)&Bs3[wc * 64 + n * 16 + (lane & 15)][chk * 8];
      }
#pragma unroll
      for (int m = 0; m < 4; m++)
#pragma unroll
        for (int n = 0; n < 4; n++) {
          acc1[m][n] = __builtin_amdgcn_mfma_f32_16x16x32_bf16(af[m], b1f[n], acc1[m][n], 0, 0, 0);
          acc3[m][n] = __builtin_amdgcn_mfma_f32_16x16x32_bf16(af[m], b3f[n], acc3[m][n], 0, 0, 0);
        }
    }
  }
#pragma unroll
  for (int m = 0; m < 4; m++) {
#pragma unroll
    for (int r = 0; r < 4; r++) {
      int row_local = wr * 64 + m * 16 + (lane >> 4) * 4 + r;
      if (row_local < rows) {
        size_t rowp = (size_t)(slot_base + row_local) * hld + n0 + wc * 64 + (lane & 15);
#pragma unroll
        for (int n = 0; n < 4; n++) {
          float c1 = acc1[m][n][r], c3 = acc3[m][n][r];
          float hval = (c1 / (1.f + __expf(-c1))) * c3;
          out[rowp + n * 16] = f2bf(hval);
        }
      }
    }
  }
}

// down-GEMM: routed O = H W2^T (scaled by pw, bf16 slotout); shared y = Hs sw2^T
__global__ __launch_bounds__(256, 2)
void down2m_k(const u16* __restrict__ H, const u16* __restrict__ Hs,
              const u16* __restrict__ w2b, const u16* __restrict__ sw2b,
              const int4* __restrict__ desc, const int* __restrict__ ntiles,
              const float* __restrict__ pw,
              u16* __restrict__ slotout, float* __restrict__ yout)
{
  int bid = blockIdx.x;
  bool routed = bid < DN_RSEG;
  int slot_base, rows, n0, kd, ksteps;
  const u16 *A0, *B;
  if (routed) {
    int rt0 = bid % 416, ct = bid / 416;
    int rt = (rt0 & 7) * 52 + (rt0 >> 3);
    if (rt >= ntiles[0]) return;
    int4 d = desc[rt];
    slot_base = d.y; rows = d.z;
    A0 = H; B = w2b + (size_t)d.x * DIM * INTER;
    n0 = ct * 128; kd = INTER; ksteps = INTER / 64;
  } else {
    int b2 = bid - DN_RSEG;
    int rt0 = b2 & 63, ct = b2 >> 6;             // 64 row tiles, 16 col tiles
    int rt = (rt0 & 7) * 8 + (rt0 >> 3);
    slot_base = rt * 128; rows = 128;
    A0 = Hs; B = sw2b;
    n0 = ct * 128; kd = SHINTER; ksteps = SHINTER / 64;
  }
  int tid = threadIdx.x, lane = tid & 63;
  int w = tid >> 6, wr = w >> 1, wc = w & 1;
  __shared__ u16 As[128][64];
  __shared__ u16 Bs[128][64];

  int selem = (((lane & 7) ^ (lane >> 3)) * 8);
  const u16 *a_src[4], *b_src[4];
#pragma unroll
  for (int s = 0; s < 4; s++) {
    int r = w * 32 + s * 8 + (lane >> 3);
    a_src[s] = A0 + (size_t)(slot_base + r) * kd + selem;
    b_src[s] = B + (size_t)(n0 + r) * kd + selem;
  }

  f32x4 acc[4][4];
#pragma unroll
  for (int m = 0; m < 4; m++)
#pragma unroll
    for (int n = 0; n < 4; n++) acc[m][n] = {0.f,0.f,0.f,0.f};

  for (int kk = 0; kk < ksteps; kk++) {
    __syncthreads();
#pragma unroll
    for (int s = 0; s < 4; s++) {
      gl16(a_src[s] + kk * 64, &As[w * 32 + s * 8][0]);
      gl16(b_src[s] + kk * 64, &Bs[w * 32 + s * 8][0]);
    }
    __syncthreads();
#pragma unroll
    for (int h = 0; h < 2; h++) {
      bf16x8 af[4], bfv[4];
      int chk = (h * 4 + (lane >> 4)) ^ (lane & 7);
#pragma unroll
      for (int m = 0; m < 4; m++)
        af[m] = *(const bf16x8*)&As[wr * 64 + m * 16 + (lane & 15)][chk * 8];
#pragma unroll
      for (int n = 0; n < 4; n++)
        bfv[n] = *(const bf16x8*)&Bs[wc * 64 + n * 16 + (lane & 15)][chk * 8];
#pragma unroll
      for (int m = 0; m < 4; m++)
#pragma unroll
        for (int n = 0; n < 4; n++)
          acc[m][n] = __builtin_amdgcn_mfma_f32_16x16x32_bf16(af[m], bfv[n], acc[m][n], 0, 0, 0);
    }
  }
#pragma unroll
  for (int m = 0; m < 4; m++) {
#pragma unroll
    for (int r = 0; r < 4; r++) {
      int row_local = wr * 64 + m * 16 + (lane >> 4) * 4 + r;
      if (row_local < rows) {
        int slot = slot_base + row_local;
        size_t rp = (size_t)slot * DIM + n0 + wc * 64 + (lane & 15);
        if (routed) {
          float sw = pw[slot];
#pragma unroll
          for (int n = 0; n < 4; n++) slotout[rp + n * 16] = f2bf(acc[m][n][r] * sw);
        } else {
#pragma unroll
          for (int n = 0; n < 4; n++) yout[rp + n * 16] = acc[m][n][r];
        }
      }
    }
  }
}

// ============================================================================
// FALLBACK PATH (f32 weights, 128^2 reg-staged) — used only if ws too small
// ============================================================================
template<bool SHARED>
__global__ __launch_bounds__(256, 2)
void up_gemm_k(const u16* __restrict__ xb,
               const float* __restrict__ W1g, const float* __restrict__ W3g,
               const int* __restrict__ ptok,
               const int4* __restrict__ desc, const int* __restrict__ ntiles,
               u16* __restrict__ Hout)
{
  constexpr int HLD = SHARED ? SHINTER : INTER;
  int row_tile = blockIdx.x, col_tile = blockIdx.y;
  int slot_base, rows;
  const float *B1, *B3;
  if constexpr (SHARED) {
    slot_base = row_tile * 128; rows = 128; B1 = W1g; B3 = W3g;
  } else {
    if (row_tile >= ntiles[0]) return;
    int4 d = desc[row_tile];
    slot_base = d.y; rows = d.z;
    size_t off = (size_t)d.x * (size_t)INTER * DIM;
    B1 = W1g + off; B3 = W3g + off;
  }
  int n0 = col_tile * 128;
  int tid = threadIdx.x, lane = tid & 63;
  int wv = tid >> 6, wr = wv >> 1, wc = wv & 1;

  __shared__ u16 As[128][72];
  __shared__ u16 Bs1[128][72];
  __shared__ u16 Bs3[128][72];

  int ar = tid >> 3, ac = (tid & 7) * 8;
  const u16* asrc[4];
#pragma unroll
  for (int s = 0; s < 4; s++) {
    int r = s * 32 + ar;
    int tok;
    if constexpr (SHARED) tok = slot_base + r;
    else { int rr = r < rows ? r : rows - 1; tok = ptok[slot_base + rr]; }
    asrc[s] = xb + (size_t)tok * DIM + ac;
  }
  int br = tid >> 4, bc = (tid & 15) * 4;
  const float* b1p = B1 + (size_t)(n0 + br) * DIM + bc;
  const float* b3p = B3 + (size_t)(n0 + br) * DIM + bc;

  f32x4 acc1[4][4], acc3[4][4];
#pragma unroll
  for (int m = 0; m < 4; m++)
#pragma unroll
    for (int n = 0; n < 4; n++) { acc1[m][n] = {0.f,0.f,0.f,0.f}; acc3[m][n] = {0.f,0.f,0.f,0.f}; }

  for (int kk = 0; kk < DIM / 64; kk++) {
    __syncthreads();
#pragma unroll
    for (int s = 0; s < 4; s++) {
      uint4 v = *(const uint4*)(asrc[s] + kk * 64);
      *(uint4*)&As[s * 32 + ar][ac] = v;
    }
#pragma unroll
    for (int s = 0; s < 8; s++) {
      float4 v = *(const float4*)(b1p + (size_t)(s * 16) * DIM + kk * 64);
      union { u16 h[4]; uint2 q; } o;
      o.h[0] = f2bf(v.x); o.h[1] = f2bf(v.y); o.h[2] = f2bf(v.z); o.h[3] = f2bf(v.w);
      *(uint2*)&Bs1[s * 16 + br][bc] = o.q;
    }
#pragma unroll
    for (int s = 0; s < 8; s++) {
      float4 v = *(const float4*)(b3p + (size_t)(s * 16) * DIM + kk * 64);
      union { u16 h[4]; uint2 q; } o;
      o.h[0] = f2bf(v.x); o.h[1] = f2bf(v.y); o.h[2] = f2bf(v.z); o.h[3] = f2bf(v.w);
      *(uint2*)&Bs3[s * 16 + br][bc] = o.q;
    }
    __syncthreads();
#pragma unroll
    for (int h = 0; h < 2; h++) {
      bf16x8 af[4], b1f[4], b3f[4];
#pragma unroll
      for (int m = 0; m < 4; m++)
        af[m] = *(const bf16x8*)&As[wr * 64 + m * 16 + (lane & 15)][h * 32 + (lane >> 4) * 8];
#pragma unroll
      for (int n = 0; n < 4; n++) {
        b1f[n] = *(const bf16x8*)&Bs1[wc * 64 + n * 16 + (lane & 15)][h * 32 + (lane >> 4) * 8];
        b3f[n] = *(const bf16x8*)&Bs3[wc * 64 + n * 16 + (lane & 15)][h * 32 + (lane >> 4) * 8];
      }
#pragma unroll
      for (int m = 0; m < 4; m++)
#pragma unroll
        for (int n = 0; n < 4; n++) {
          acc1[m][n] = __builtin_amdgcn_mfma_f32_16x16x32_bf16(af[m], b1f[n], acc1[m][n], 0, 0, 0);
          acc3[m][n] = __builtin_amdgcn_mfma_f32_16x16x32_bf16(af[m], b3f[n], acc3[m][n], 0, 0, 0);
        }
    }
  }
#pragma unroll
  for (int m = 0; m < 4; m++) {
#pragma unroll
    for (int r = 0; r < 4; r++) {
      int row_local = wr * 64 + m * 16 + (lane >> 4) * 4 + r;
      if (row_local < rows) {
        size_t rowp = (size_t)(slot_base + row_local) * HLD + n0 + wc * 64 + (lane & 15);
#pragma unroll
        for (int n = 0; n < 4; n++) {
          float c1 = acc1[m][n][r], c3 = acc3[m][n][r];
          float hval = (c1 / (1.f + __expf(-c1))) * c3;
          Hout[rowp + n * 16] = f2bf(hval);
        }
      }
    }
  }
}

template<bool SHARED>
__global__ __launch_bounds__(256, 2)
void down_gemm_k(const u16* __restrict__ Hin, const float* __restrict__ Bg,
                 const int4* __restrict__ desc, const int* __restrict__ ntiles,
                 const float* __restrict__ pw,
                 u16* __restrict__ slotout, float* __restrict__ yout)
{
  constexpr int KD = SHARED ? SHINTER : INTER;
  constexpr int KSTEPS = KD / 64;
  int row_tile = blockIdx.x, col_tile = blockIdx.y;
  int slot_base, rows; const float* B;
  if constexpr (SHARED) { slot_base = row_tile * 128; rows = 128; B = Bg; }
  else {
    if (row_tile >= ntiles[0]) return;
    int4 d = desc[row_tile]; slot_base = d.y; rows = d.z;
    B = Bg + (size_t)d.x * DIM * INTER;
  }
  int n0 = col_tile * 128;
  int tid = threadIdx.x, lane = tid & 63;
  int wv = tid >> 6, wr = wv >> 1, wc = wv & 1;
  __shared__ u16 As[128][72];
  __shared__ u16 Bs[128][72];
  int ar = tid >> 3, ac = (tid & 7) * 8;
  const u16* asrc[4];
#pragma unroll
  for (int s = 0; s < 4; s++)
    asrc[s] = Hin + (size_t)(slot_base + s * 32 + ar) * KD + ac;
  int br = tid >> 4, bc = (tid & 15) * 4;
  const float* bp = B + (size_t)(n0 + br) * KD + bc;

  f32x4 acc[4][4];
#pragma unroll
  for (int m = 0; m < 4; m++)
#pragma unroll
    for (int n = 0; n < 4; n++) acc[m][n] = {0.f,0.f,0.f,0.f};

  for (int kk = 0; kk < KSTEPS; kk++) {
    __syncthreads();
#pragma unroll
    for (int s = 0; s < 4; s++) {
      uint4 v = *(const uint4*)(asrc[s] + kk * 64);
      *(uint4*)&As[s * 32 + ar][ac] = v;
    }
#pragma unroll
    for (int s = 0; s < 8; s++) {
      float4 v = *(const float4*)(bp + (size_t)(s * 16) * KD + kk * 64);
      union { u16 h[4]; uint2 q; } o;
      o.h[0] = f2bf(v.x); o.h[1] = f2bf(v.y); o.h[2] = f2bf(v.z); o.h[3] = f2bf(v.w);
      *(uint2*)&Bs[s * 16 + br][bc] = o.q;
    }
    __syncthreads();
#pragma unroll
    for (int h = 0; h < 2; h++) {
      bf16x8 af[4], bfv[4];
#pragma unroll
      for (int m = 0; m < 4; m++)
        af[m] = *(const bf16x8*)&As[wr * 64 + m * 16 + (lane & 15)][h * 32 + (lane >> 4) * 8];
#pragma unroll
      for (int n = 0; n < 4; n++)
        bfv[n] = *(const bf16x8*)&Bs[wc * 64 + n * 16 + (lane & 15)][h * 32 + (lane >> 4) * 8];
#pragma unroll
      for (int m = 0; m < 4; m++)
#pragma unroll
        for (int n = 0; n < 4; n++)
          acc[m][n] = __builtin_amdgcn_mfma_f32_16x16x32_bf16(af[m], bfv[n], acc[m][n], 0, 0, 0);
    }
  }
#pragma unroll
  for (int m = 0; m < 4; m++) {
#pragma unroll
    for (int r = 0; r < 4; r++) {
      int row_local = wr * 64 + m * 16 + (lane >> 4) * 4 + r;
      if (row_local < rows) {
        int slot = slot_base + row_local;
        size_t rp = (size_t)slot * DIM + n0 + wc * 64 + (lane & 15);
        if constexpr (SHARED) {
#pragma unroll
          for (int n = 0; n < 4; n++) yout[rp + n * 16] = acc[m][n][r];
        } else {
          float sw = pw[slot];
#pragma unroll
          for (int n = 0; n < 4; n++) slotout[rp + n * 16] = f2bf(acc[m][n][r] * sw);
        }
      }
    }
  }
}

// ---------------- final combine: y[t] = shared + sum_k slotout ----------------
__global__ __launch_bounds__(256)
void combine_k(float* __restrict__ y, const u16* __restrict__ slotout, const int* __restrict__ slotof)
{
  int t = blockIdx.x;
  int c = threadIdx.x * 8;
  size_t rp = (size_t)t * DIM + c;
  float4 a = *(const float4*)(y + rp);
  float4 b = *(const float4*)(y + rp + 4);
  float o[8] = {a.x, a.y, a.z, a.w, b.x, b.y, b.z, b.w};
#pragma unroll
  for (int k = 0; k < TOPK; k++) {
    int s = slotof[t * TOPK + k];
    uint4 v = *(const uint4*)(slotout + (size_t)s * DIM + c);
    o[0] += bf2f((u16)(v.x & 0xFFFFu)); o[1] += bf2f((u16)(v.x >> 16));
    o[2] += bf2f((u16)(v.y & 0xFFFFu)); o[3] += bf2f((u16)(v.y >> 16));
    o[4] += bf2f((u16)(v.z & 0xFFFFu)); o[5] += bf2f((u16)(v.z >> 16));
    o[6] += bf2f((u16)(v.w & 0xFFFFu)); o[7] += bf2f((u16)(v.w >> 16));
  }
  *(float4*)(y + rp)     = make_float4(o[0], o[1], o[2], o[3]);
  *(float4*)(y + rp + 4) = make_float4(o[4], o[5], o[6], o[7]);
}

// ---------------- host ----------------
extern "C" void kernel_launch(void* const* d_in, const int* in_sizes, int n_in,
                              void* d_out, int out_size, void* d_ws, size_t ws_size,
                              hipStream_t stream)
{
  const float* x   = (const float*)d_in[0];
  const float* gw  = (const float*)d_in[1];
  const float* w1  = (const float*)d_in[2];
  const float* w2  = (const float*)d_in[3];
  const float* w3  = (const float*)d_in[4];
  const float* sw1 = (const float*)d_in[5];
  const float* sw2 = (const float*)d_in[6];
  const float* sw3 = (const float*)d_in[7];
  float* y = (float*)d_out;
  char* ws = (char*)d_ws;

  int*   counts  = (int*)(ws + 0);
  int*   ntiles  = (int*)(ws + 256);
  int*   offs    = (int*)(ws + 512);
  int4*  desc128 = (int4*)(ws + 1024);
  int*   tidx    = (int*)(ws + 16384);
  float* tw      = (float*)(ws + 212992);
  int*   ptok    = (int*)(ws + 409600);
  float* pw      = (float*)(ws + 606208);
  int*   slotof  = (int*)(ws + 802816);
  u16*   xb      = (u16*)(ws + 1048576);
  u16*   H       = (u16*)(ws + 34603008ull);
  u16*   Hs      = (u16*)(ws + 173735936ull);
  u16*   sout    = (u16*)(ws + 219873280ull);
  u16*   w1b     = (u16*)(ws + 421199872ull);
  u16*   w3b     = (u16*)(ws + 605749248ull);
  u16*   w2b     = (u16*)(ws + 790298624ull);
  u16*   sw1b    = (u16*)(ws + 974848000ull);
  u16*   sw3b    = (u16*)(ws + 986382336ull);
  u16*   sw2b    = (u16*)(ws + 997916672ull);
  const unsigned long long NEED_FULL = 1009451008ull;

  zero32<<<1, 64, 0, stream>>>(counts);
  gate_route_k<<<2048, 256, 0, stream>>>(x, gw, tidx, tw, counts, xb);
  scan_desc_k<<<1, 64, 0, stream>>>(counts, offs, desc128, ntiles);
  perm_build_k<<<32, 1024, 0, stream>>>(tidx, tw, offs, ptok, pw, slotof);

  if (ws_size >= NEED_FULL) {
    const int NW = NEXP * INTER * DIM / 8;
    const int NS = SHINTER * DIM / 8;
    cvt3_k<<<dim3(4096, 3), 256, 0, stream>>>(w1, w3, w2, w1b, w3b, w2b, NW);
    cvt3_k<<<dim3(1024, 3), 256, 0, stream>>>(sw1, sw3, sw2, sw1b, sw3b, sw2b, NS);

    up2m_k<<<UP_RSEG + 64 * 22, 256, 0, stream>>>(xb, w1b, w3b, sw1b, sw3b,
                                                  ptok, desc128, ntiles, H, Hs);
    down2m_k<<<DN_RSEG + 64 * 16, 256, 0, stream>>>(H, Hs, w2b, sw2b,
                                                    desc128, ntiles, pw, sout, y);
  } else {
    up_gemm_k<false><<<dim3(416, 11), 256, 0, stream>>>(xb, w1, w3, ptok, desc128, ntiles, H);
    up_gemm_k<true ><<<dim3(64, 22), 256, 0, stream>>>(xb, sw1, sw3, ptok, desc128, ntiles, Hs);
    down_gemm_k<true ><<<dim3(64, 16), 256, 0, stream>>>(Hs, sw2, desc128, ntiles, pw, sout, y);
    down_gemm_k<false><<<dim3(416, 16), 256, 0, stream>>>(H, w2, desc128, ntiles, pw, sout, y);
  }

  combine_k<<<8192, 256, 0, stream>>>(y, sout, slotof);
}